// Round 1
// baseline (696.039 us; speedup 1.0000x reference)
//
#include <hip/hip_runtime.h>

#define B_ROWS 8192
#define IN_DIM 2048
#define H_DIM  2048
#define K_DIM  4096              // IN + H
#define CH_OFF (B_ROWS * H_DIM)  // offset of h_t in d_out

typedef __attribute__((ext_vector_type(8))) short bf16x8;
typedef __attribute__((ext_vector_type(8))) short short8;
typedef __attribute__((ext_vector_type(4))) float f32x4;

// fp32 -> bf16 round-to-nearest-even
static __device__ __forceinline__ unsigned short f2bf(float f) {
  union { float f; unsigned u; } v; v.f = f;
  unsigned r = v.u + 0x7fffu + ((v.u >> 16) & 1u);
  return (unsigned short)(r >> 16);
}

// async 16B global -> LDS (wave-uniform base + lane*16 on the LDS side)
static __device__ __forceinline__ void load_lds16(const void* g, void* l) {
  __builtin_amdgcn_global_load_lds(
      (const __attribute__((address_space(1))) unsigned int*)(unsigned long long)(uintptr_t)g,
      (__attribute__((address_space(3))) unsigned int*)(unsigned int)(uintptr_t)l,
      16, 0, 0);
}

// ---------------------------------------------------------------------------
// Pack [input | hidden] (fp32) -> A bf16 [8192][4096]
// ---------------------------------------------------------------------------
__global__ __launch_bounds__(256) void pack_act(
    const float* __restrict__ inp, const float* __restrict__ hid,
    short* __restrict__ out) {
  int idx = blockIdx.x * 256 + threadIdx.x;   // one 8-elem chunk per thread
  int m = idx >> 9;                           // 512 chunks per 4096-row
  int k = (idx & 511) * 8;
  const float* s = (k < IN_DIM) ? (inp + m * IN_DIM + k)
                                : (hid + m * H_DIM + (k - IN_DIM));
  float4 a = *(const float4*)s;
  float4 c = *(const float4*)(s + 4);
  short8 o;
  o[0] = (short)f2bf(a.x); o[1] = (short)f2bf(a.y);
  o[2] = (short)f2bf(a.z); o[3] = (short)f2bf(a.w);
  o[4] = (short)f2bf(c.x); o[5] = (short)f2bf(c.y);
  o[6] = (short)f2bf(c.z); o[7] = (short)f2bf(c.w);
  *(short8*)(out + (size_t)idx * 8) = o;
}

// ---------------------------------------------------------------------------
// Pack + transpose weights: W[k][h] fp32 -> WT[gate][h][k] bf16 [4][2048][4096]
// k < 2048: input-to-hidden weights; k >= 2048: hidden-to-hidden weights
// ---------------------------------------------------------------------------
__global__ __launch_bounds__(256) void pack_w(
    const float* __restrict__ wi0, const float* __restrict__ wi1,
    const float* __restrict__ wi2, const float* __restrict__ wi3,
    const float* __restrict__ wh0, const float* __restrict__ wh1,
    const float* __restrict__ wh2, const float* __restrict__ wh3,
    short* __restrict__ out) {
  __shared__ float tileS[64][65];   // +1 pad: 2-way bank aliasing only (free)
  int b = blockIdx.x;
  int w = b >> 10;                  // 0..7: which source matrix
  int tile = b & 1023;
  int tk = tile >> 5;               // 32 k-tiles of 64
  int th = tile & 31;               // 32 h-tiles of 64
  const float* src;
  switch (w) {
    case 0: src = wi0; break; case 1: src = wi1; break;
    case 2: src = wi2; break; case 3: src = wi3; break;
    case 4: src = wh0; break; case 5: src = wh1; break;
    case 6: src = wh2; break; default: src = wh3; break;
  }
  int g = w & 3, half = w >> 2;
  int t = threadIdx.x;
  // coalesced fp32 load of the 64x64 source tile
  #pragma unroll
  for (int it = 0; it < 4; ++it) {
    int idx = it * 256 + t;
    int sr = idx >> 4, sc = idx & 15;
    float4 v = *(const float4*)(src + (tk * 64 + sr) * H_DIM + th * 64 + sc * 4);
    tileS[sr][sc * 4 + 0] = v.x; tileS[sr][sc * 4 + 1] = v.y;
    tileS[sr][sc * 4 + 2] = v.z; tileS[sr][sc * 4 + 3] = v.w;
  }
  __syncthreads();
  // transposed bf16 store, 8 k per thread (coalesced 16B stores)
  #pragma unroll
  for (int it = 0; it < 2; ++it) {
    int idx = it * 256 + t;         // 0..511
    int orow = idx >> 3;            // h within tile
    int okg = idx & 7;              // 8-k group
    short8 o;
    #pragma unroll
    for (int j = 0; j < 8; ++j) o[j] = (short)f2bf(tileS[okg * 8 + j][orow]);
    int off = (g * H_DIM + th * 64 + orow) * K_DIM + half * IN_DIM + tk * 64 + okg * 8;
    *(short8*)(out + off) = o;
  }
}

// ---------------------------------------------------------------------------
// Fused GEMM (bf16 MFMA) + LSTM epilogue.
// Block: 128 rows x 64 h-cols, 4 gate accumulator sets sharing the A tile.
// ---------------------------------------------------------------------------
__global__ __launch_bounds__(256, 2) void lstm_gemm(
    const short* __restrict__ actB,   // [8192][4096] bf16
    const short* __restrict__ wB,     // [4][2048][4096] bf16 (W^T per gate)
    const float* __restrict__ cprev,  // [8192][2048]
    const float* __restrict__ bi_p, const float* __restrict__ bf_p,
    const float* __restrict__ bg_p, const float* __restrict__ bo_p,
    float* __restrict__ out) {        // c_t then h_t
  __shared__ __align__(16) short As[128 * 64];       // 16 KB, XOR-swizzled
  __shared__ __align__(16) short Bs[4 * 64 * 64];    // 32 KB, XOR-swizzled

  int bid = blockIdx.x;
  int swz = (bid & 7) * 256 + (bid >> 3);  // bijective XCD swizzle (2048 % 8 == 0)
  int mrow = swz >> 5;                     // 64 row-blocks
  int hb = swz & 31;                       // 32 h-blocks
  int m0 = mrow * 128;
  int h0 = hb * 64;

  int t = threadIdx.x;
  int lane = t & 63;
  int wid = t >> 6;
  int wm = wid >> 1, wh = wid & 1;         // 2x2 wave grid: 64 rows x 32 h per wave
  int q = lane >> 4, cl = lane & 15;

  f32x4 zero = {0.f, 0.f, 0.f, 0.f};
  f32x4 acc[4][4][2];                      // [gate][mi][hi]
  #pragma unroll
  for (int g = 0; g < 4; ++g)
    #pragma unroll
    for (int mi = 0; mi < 4; ++mi)
      #pragma unroll
      for (int hi = 0; hi < 2; ++hi) acc[g][mi][hi] = zero;

  const short* aB = actB + m0 * K_DIM;
  const short* bB = wB + h0 * K_DIM;

  for (int kt = 0; kt < K_DIM / 64; ++kt) {
    int k0 = kt * 64;
    __syncthreads();
    // stage A tile 128x64 (16B chunks; source pre-swizzled so LDS dest is linear)
    #pragma unroll
    for (int it = 0; it < 4; ++it) {
      int idx = it * 256 + t;
      int r = idx >> 3, cS = idx & 7;
      int c = cS ^ (r & 7);
      load_lds16(aB + r * K_DIM + k0 + c * 8, (char*)As + idx * 16);
    }
    // stage B tiles: 4 gates x 64h x 64k
    #pragma unroll
    for (int it = 0; it < 8; ++it) {
      int idx = it * 256 + t;
      int gg = idx >> 9, j = idx & 511;
      int r = j >> 3, cS = j & 7;
      int c = cS ^ (r & 7);
      load_lds16(bB + gg * (H_DIM * K_DIM) + r * K_DIM + k0 + c * 8,
                 (char*)Bs + idx * 16);
    }
    __syncthreads();
    // compute: 2 K-steps of 32
    #pragma unroll
    for (int s = 0; s < 2; ++s) {
      bf16x8 af[4], bfr[4][2];
      #pragma unroll
      for (int mi = 0; mi < 4; ++mi) {
        int r = wm * 64 + mi * 16 + cl;
        int ch = (s * 4 + q) ^ (r & 7);
        af[mi] = *(const bf16x8*)((const char*)As + r * 128 + ch * 16);
      }
      #pragma unroll
      for (int g = 0; g < 4; ++g)
        #pragma unroll
        for (int hi = 0; hi < 2; ++hi) {
          int r = wh * 32 + hi * 16 + cl;
          int ch = (s * 4 + q) ^ (r & 7);
          bfr[g][hi] = *(const bf16x8*)((const char*)Bs + g * 8192 + r * 128 + ch * 16);
        }
      #pragma unroll
      for (int g = 0; g < 4; ++g)
        #pragma unroll
        for (int mi = 0; mi < 4; ++mi)
          #pragma unroll
          for (int hi = 0; hi < 2; ++hi)
            acc[g][mi][hi] = __builtin_amdgcn_mfma_f32_16x16x32_bf16(
                af[mi], bfr[g][hi], acc[g][mi][hi], 0, 0, 0);
    }
  }

  // epilogue: lane holds i,f,g,o pre-activations for the SAME (row, h)
  #pragma unroll
  for (int hi = 0; hi < 2; ++hi) {
    int hg = h0 + wh * 32 + hi * 16 + cl;
    float vbi = bi_p[hg], vbf = bf_p[hg], vbg = bg_p[hg], vbo = bo_p[hg];
    #pragma unroll
    for (int mi = 0; mi < 4; ++mi) {
      #pragma unroll
      for (int r = 0; r < 4; ++r) {
        int mg = m0 + wm * 64 + mi * 16 + q * 4 + r;
        float pi = acc[0][mi][hi][r] + vbi;
        float pf = acc[1][mi][hi][r] + vbf;
        float pg = acc[2][mi][hi][r] + vbg;
        float po = acc[3][mi][hi][r] + vbo;
        // NaN-safe fast sigmoid/tanh (inf-tolerant forms)
        float iv = 1.f / (1.f + __expf(-pi));
        float fv = 1.f / (1.f + __expf(-pf));
        float gv = 1.f - 2.f / (__expf(2.f * pg) + 1.f);
        float ov = 1.f / (1.f + __expf(-po));
        float cp = cprev[mg * H_DIM + hg];
        float cv = fv * cp + iv * gv;
        float tc = 1.f - 2.f / (__expf(2.f * cv) + 1.f);
        out[mg * H_DIM + hg] = cv;
        out[CH_OFF + mg * H_DIM + hg] = ov * tc;
      }
    }
  }
}

extern "C" void kernel_launch(void* const* d_in, const int* in_sizes, int n_in,
                              void* d_out, int out_size, void* d_ws, size_t ws_size,
                              hipStream_t stream) {
  const float* inp   = (const float*)d_in[0];
  const float* hid   = (const float*)d_in[1];
  const float* cprev = (const float*)d_in[2];
  short* actB = (short*)d_ws;                          // 64 MB bf16
  short* wB   = actB + (size_t)B_ROWS * K_DIM;         // 64 MB bf16

  pack_act<<<dim3(B_ROWS * K_DIM / 8 / 256), dim3(256), 0, stream>>>(inp, hid, actB);
  pack_w<<<dim3(8 * 1024), dim3(256), 0, stream>>>(
      (const float*)d_in[3], (const float*)d_in[4],
      (const float*)d_in[5], (const float*)d_in[6],
      (const float*)d_in[7], (const float*)d_in[8],
      (const float*)d_in[9], (const float*)d_in[10], wB);
  lstm_gemm<<<dim3(2048), dim3(256), 0, stream>>>(
      actB, wB, cprev,
      (const float*)d_in[11], (const float*)d_in[12],
      (const float*)d_in[13], (const float*)d_in[14],
      (float*)d_out);
}

// Round 2
// 630.376 us; speedup vs baseline: 1.1042x; 1.1042x over previous
//
#include <hip/hip_runtime.h>

#define B_ROWS 8192
#define IN_DIM 2048
#define H_DIM  2048
#define K_DIM  4096              // IN + H
#define CH_OFF (B_ROWS * H_DIM)  // offset of h_t in d_out
#define NT     (K_DIM / 32)      // 128 K-tiles of depth 32

typedef __attribute__((ext_vector_type(8))) short bf16x8;
typedef __attribute__((ext_vector_type(8))) short short8;
typedef __attribute__((ext_vector_type(4))) float f32x4;

// fp32 -> bf16 round-to-nearest-even
static __device__ __forceinline__ unsigned short f2bf(float f) {
  union { float f; unsigned u; } v; v.f = f;
  unsigned r = v.u + 0x7fffu + ((v.u >> 16) & 1u);
  return (unsigned short)(r >> 16);
}

// async 16B global -> LDS (wave-uniform base + lane*16 on the LDS side)
static __device__ __forceinline__ void load_lds16(const void* g, void* l) {
  __builtin_amdgcn_global_load_lds(
      (const __attribute__((address_space(1))) unsigned int*)(unsigned long long)(uintptr_t)g,
      (__attribute__((address_space(3))) unsigned int*)(unsigned int)(uintptr_t)l,
      16, 0, 0);
}

// raw barrier — no vmcnt(0) drain (T4); memory clobber pins compiler ordering
static __device__ __forceinline__ void bar() {
  asm volatile("s_barrier" ::: "memory");
}

// ---------------------------------------------------------------------------
// Pack [input | hidden] (fp32) -> A bf16 [8192][4096]
// ---------------------------------------------------------------------------
__global__ __launch_bounds__(256) void pack_act(
    const float* __restrict__ inp, const float* __restrict__ hid,
    short* __restrict__ out) {
  int idx = blockIdx.x * 256 + threadIdx.x;
  int m = idx >> 9;
  int k = (idx & 511) * 8;
  const float* s = (k < IN_DIM) ? (inp + m * IN_DIM + k)
                                : (hid + m * H_DIM + (k - IN_DIM));
  float4 a = *(const float4*)s;
  float4 c = *(const float4*)(s + 4);
  short8 o;
  o[0] = (short)f2bf(a.x); o[1] = (short)f2bf(a.y);
  o[2] = (short)f2bf(a.z); o[3] = (short)f2bf(a.w);
  o[4] = (short)f2bf(c.x); o[5] = (short)f2bf(c.y);
  o[6] = (short)f2bf(c.z); o[7] = (short)f2bf(c.w);
  *(short8*)(out + (size_t)idx * 8) = o;
}

// ---------------------------------------------------------------------------
// Pack + transpose weights -> WT[n][k] bf16, n = (h>>4)*64 + gate*16 + (h&15)
// so a 16-col MFMA fragment = one gate, and consecutive 64-col groups hold the
// 4 gates of the same 16 h values (epilogue becomes lane-local).
// ---------------------------------------------------------------------------
__global__ __launch_bounds__(256) void pack_w(
    const float* __restrict__ wi0, const float* __restrict__ wi1,
    const float* __restrict__ wi2, const float* __restrict__ wi3,
    const float* __restrict__ wh0, const float* __restrict__ wh1,
    const float* __restrict__ wh2, const float* __restrict__ wh3,
    short* __restrict__ out) {
  __shared__ float tileS[64][65];
  int b = blockIdx.x;
  int w = b >> 10;
  int tile = b & 1023;
  int tk = tile >> 5;
  int th = tile & 31;
  const float* src;
  switch (w) {
    case 0: src = wi0; break; case 1: src = wi1; break;
    case 2: src = wi2; break; case 3: src = wi3; break;
    case 4: src = wh0; break; case 5: src = wh1; break;
    case 6: src = wh2; break; default: src = wh3; break;
  }
  int g = w & 3, half = w >> 2;
  int t = threadIdx.x;
  #pragma unroll
  for (int it = 0; it < 4; ++it) {
    int idx = it * 256 + t;
    int sr = idx >> 4, sc = idx & 15;
    float4 v = *(const float4*)(src + (tk * 64 + sr) * H_DIM + th * 64 + sc * 4);
    tileS[sr][sc * 4 + 0] = v.x; tileS[sr][sc * 4 + 1] = v.y;
    tileS[sr][sc * 4 + 2] = v.z; tileS[sr][sc * 4 + 3] = v.w;
  }
  __syncthreads();
  #pragma unroll
  for (int it = 0; it < 2; ++it) {
    int idx = it * 256 + t;
    int orow = idx >> 3;
    int okg = idx & 7;
    short8 o;
    #pragma unroll
    for (int j = 0; j < 8; ++j) o[j] = (short)f2bf(tileS[okg * 8 + j][orow]);
    int hg = th * 64 + orow;
    int n = (hg >> 4) * 64 + g * 16 + (hg & 15);
    int off = n * K_DIM + half * IN_DIM + tk * 64 + okg * 8;
    *(short8*)(out + off) = o;
  }
}

// ---------------------------------------------------------------------------
// Fused GEMM (bf16 MFMA) + LSTM epilogue, 8-phase-style deep pipeline.
// 256x256 tile, BK=32, 4-slot LDS rotation, counted vmcnt(8), setprio.
// ---------------------------------------------------------------------------
__global__ __launch_bounds__(512, 2) void lstm_gemm(
    const short* __restrict__ actB,   // [8192][4096] bf16
    const short* __restrict__ wB,     // [8192][4096] bf16 packed W^T
    const float* __restrict__ cprev,
    const float* __restrict__ bi_p, const float* __restrict__ bf_p,
    const float* __restrict__ bg_p, const float* __restrict__ bo_p,
    float* __restrict__ out) {
  // slot layout: row r' (0..127) holds 128B = two half-rows (m=r', m=r'+128),
  // 8 chunks of 16B, chunk XOR-swizzled with (r'&7). 4 slots x 16KB per operand.
  __shared__ __align__(16) short As[4][8192];   // 64 KB
  __shared__ __align__(16) short Bs[4][8192];   // 64 KB

  int bid = blockIdx.x;
  int swz = (bid & 7) * 128 + (bid >> 3);   // bijective XCD swizzle (1024%8==0)
  int mblk = swz >> 5, nblk = swz & 31;
  int m0 = mblk * 256;
  int n0 = nblk * 256;

  int t = threadIdx.x;
  int lane = t & 63, wid = t >> 6;
  int wm = wid >> 2, wn = wid & 3;          // 2M x 4N wave grid
  int q = lane >> 4, cl = lane & 15;

  // --- staging: per thread 2 A-chunks + 2 B-chunks per K-tile (16B each) ---
  const short* aS[2]; const short* bS[2];
  char* aD[2]; char* bD[2];
  #pragma unroll
  for (int it = 0; it < 2; ++it) {
    int idx = it * 512 + t;
    int rp = idx >> 3, c = idx & 7;
    int cu = c ^ (rp & 7);                  // logical chunk at this physical pos
    int half = cu >> 2, qq = cu & 3;
    aS[it] = actB + (size_t)(m0 + half * 128 + rp) * K_DIM + qq * 8;
    bS[it] = wB   + (size_t)(n0 + half * 128 + rp) * K_DIM + qq * 8;
    aD[it] = (char*)&As[0][0] + idx * 16;
    bD[it] = (char*)&Bs[0][0] + idx * 16;
  }
  auto stageA = [&](int kt) {
    int so = (kt & 3) * 16384, ko = kt * 32;
    load_lds16(aS[0] + ko, aD[0] + so);
    load_lds16(aS[1] + ko, aD[1] + so);
  };
  auto stageB = [&](int kt) {
    int so = (kt & 3) * 16384, ko = kt * 32;
    load_lds16(bS[0] + ko, bD[0] + so);
    load_lds16(bS[1] + ko, bD[1] + so);
  };
  // --- fragment reads (swizzled) ---
  auto ldA = [&](int sl, int rp, int cu) -> bf16x8 {
    int ch = cu ^ (rp & 7);
    return *(const bf16x8*)((const char*)&As[sl][0] + rp * 128 + ch * 16);
  };
  auto ldB = [&](int sl, int rp, int cu) -> bf16x8 {
    int ch = cu ^ (rp & 7);
    return *(const bf16x8*)((const char*)&Bs[sl][0] + rp * 128 + ch * 16);
  };

  f32x4 zero = {0.f, 0.f, 0.f, 0.f};
  f32x4 acc[8][4];
  #pragma unroll
  for (int mi = 0; mi < 8; ++mi)
    #pragma unroll
    for (int ni = 0; ni < 4; ++ni) acc[mi][ni] = zero;

  // prologue: 3 tiles in flight
  stageA(0); stageB(0); stageA(1); stageB(1); stageA(2); stageB(2);
  asm volatile("s_waitcnt vmcnt(8)" ::: "memory");   // tile 0 landed
  bar();

  int cuA = wm * 4 + q;
  int cuB = (wn >> 1) * 4 + q;
  int nb = (wn & 1) * 64;

  #pragma unroll 1
  for (int kt = 0; kt < NT; ++kt) {
    int sl = kt & 3;
    bf16x8 bfrag[4], afrag[4];
    // ---- phase 1: B frags + A frags mi 0..3, prefetch A(kt+3) ----
    #pragma unroll
    for (int ni = 0; ni < 4; ++ni) bfrag[ni] = ldB(sl, nb + ni * 16 + cl, cuB);
    #pragma unroll
    for (int mi = 0; mi < 4; ++mi) afrag[mi] = ldA(sl, mi * 16 + cl, cuA);
    if (kt + 3 < NT) stageA(kt + 3);
    bar();
    __builtin_amdgcn_sched_barrier(0);
    __builtin_amdgcn_s_setprio(1);
    #pragma unroll
    for (int mi = 0; mi < 4; ++mi)
      #pragma unroll
      for (int ni = 0; ni < 4; ++ni)
        acc[mi][ni] = __builtin_amdgcn_mfma_f32_16x16x32_bf16(
            afrag[mi], bfrag[ni], acc[mi][ni], 0, 0, 0);
    __builtin_amdgcn_s_setprio(0);
    __builtin_amdgcn_sched_barrier(0);
    bar();
    // ---- phase 2: A frags mi 4..7, prefetch B(kt+3), counted vmcnt ----
    #pragma unroll
    for (int mi = 0; mi < 4; ++mi) afrag[mi] = ldA(sl, (mi + 4) * 16 + cl, cuA);
    if (kt + 3 < NT) {
      stageB(kt + 3);
      asm volatile("s_waitcnt vmcnt(8)" ::: "memory");   // tile kt+1 landed
    } else if (kt + 3 == NT) {
      asm volatile("s_waitcnt vmcnt(4)" ::: "memory");
    } else if (kt + 2 == NT) {
      asm volatile("s_waitcnt vmcnt(0)" ::: "memory");
    }
    bar();
    __builtin_amdgcn_sched_barrier(0);
    __builtin_amdgcn_s_setprio(1);
    #pragma unroll
    for (int mi = 0; mi < 4; ++mi)
      #pragma unroll
      for (int ni = 0; ni < 4; ++ni)
        acc[mi + 4][ni] = __builtin_amdgcn_mfma_f32_16x16x32_bf16(
            afrag[mi], bfrag[ni], acc[mi + 4][ni], 0, 0, 0);
    __builtin_amdgcn_s_setprio(0);
    __builtin_amdgcn_sched_barrier(0);
    bar();
  }

  // ---- epilogue: each lane holds i,f,g,o for the same (row, h) ----
  int hg = (nblk * 4 + wn) * 16 + cl;
  float vbi = bi_p[hg], vbf = bf_p[hg], vbg = bg_p[hg], vbo = bo_p[hg];
  int mbase = m0 + wm * 128;
  #pragma unroll
  for (int mi = 0; mi < 8; ++mi) {
    #pragma unroll
    for (int r = 0; r < 4; ++r) {
      int mg = mbase + mi * 16 + q * 4 + r;
      float pi = acc[mi][0][r] + vbi;
      float pf = acc[mi][1][r] + vbf;
      float pg = acc[mi][2][r] + vbg;
      float po = acc[mi][3][r] + vbo;
      float iv = 1.f / (1.f + __expf(-pi));
      float fv = 1.f / (1.f + __expf(-pf));
      float gv = 1.f - 2.f / (__expf(2.f * pg) + 1.f);
      float ov = 1.f / (1.f + __expf(-po));
      float cp = cprev[(size_t)mg * H_DIM + hg];
      float cv = fv * cp + iv * gv;
      float tc = 1.f - 2.f / (__expf(2.f * cv) + 1.f);
      out[(size_t)mg * H_DIM + hg] = cv;
      out[CH_OFF + (size_t)mg * H_DIM + hg] = ov * tc;
    }
  }
}

extern "C" void kernel_launch(void* const* d_in, const int* in_sizes, int n_in,
                              void* d_out, int out_size, void* d_ws, size_t ws_size,
                              hipStream_t stream) {
  const float* inp   = (const float*)d_in[0];
  const float* hid   = (const float*)d_in[1];
  const float* cprev = (const float*)d_in[2];
  short* actB = (short*)d_ws;
  short* wB   = actB + (size_t)B_ROWS * K_DIM;

  pack_act<<<dim3(B_ROWS * K_DIM / 8 / 256), dim3(256), 0, stream>>>(inp, hid, actB);
  pack_w<<<dim3(8 * 1024), dim3(256), 0, stream>>>(
      (const float*)d_in[3], (const float*)d_in[4],
      (const float*)d_in[5], (const float*)d_in[6],
      (const float*)d_in[7], (const float*)d_in[8],
      (const float*)d_in[9], (const float*)d_in[10], wB);
  lstm_gemm<<<dim3(1024), dim3(512), 0, stream>>>(
      actB, wB, cprev,
      (const float*)d_in[11], (const float*)d_in[12],
      (const float*)d_in[13], (const float*)d_in[14],
      (float*)d_out);
}